// Round 18
// baseline (292.042 us; speedup 1.0000x reference)
//
#include <hip/hip_runtime.h>
#include <hip/hip_bf16.h>
#include <math.h>

typedef __hip_bfloat16 bf16;
typedef __attribute__((ext_vector_type(8))) short bf16x8;
typedef __attribute__((ext_vector_type(4))) float f32x4;

#define N_NODES 10000
#define N_EDGES 160000
#define IN_C    768
#define H1DIM   1024      // HEADS * HID
#define HEADS   4
#define OUT_C   256
#define NEG_SLOPE 0.2f

__device__ __forceinline__ float b2f(bf16 v) { return __bfloat162float(v); }
__device__ __forceinline__ float u2f(unsigned short u) { return __uint_as_float(((unsigned)u) << 16); }
__device__ __forceinline__ float lo2f(unsigned u) { return __uint_as_float(u << 16); }
__device__ __forceinline__ float hi2f(unsigned u) { return __uint_as_float(u & 0xFFFF0000u); }

// ---------------- fused prep: cvt x->bf16, transpose W1/W2, zero (r15 proven) -------
#define CVT_BLOCKS 7500                    // 10000*768/4 / 256  (exact)
#define T1_BLOCKS  768                     // (1024/32) x (768/32)
#define T2_BLOCKS  256                     // (256/32) x (1024/32)
#define Z_WORDS    140096                  // as1+ad1+as2+ad2+degs span (with carve pads)/4
#define Z_BLOCKS   548                     // ceil(Z_WORDS/256)

__global__ __launch_bounds__(256) void prep_kernel(
    const float* __restrict__ x, bf16* __restrict__ xb,
    const float* __restrict__ W1, bf16* __restrict__ W1t,
    const float* __restrict__ W2, bf16* __restrict__ W2t,
    int* __restrict__ zbase)
{
    __shared__ float tile[32][33];
    const int bid = blockIdx.x;
    const int tid = threadIdx.x;
    if (bid < CVT_BLOCKS) {
        const int i = bid * 256 + tid;
        const float4 v = *((const float4*)x + i);
        bf16* d = xb + (size_t)i * 4;
        d[0] = __float2bfloat16(v.x); d[1] = __float2bfloat16(v.y);
        d[2] = __float2bfloat16(v.z); d[3] = __float2bfloat16(v.w);
        return;
    }
    if (bid < CVT_BLOCKS + T1_BLOCKS + T2_BLOCKS) {
        const bool isW1 = bid < CVT_BLOCKS + T1_BLOCKS;
        const int lb = isW1 ? (bid - CVT_BLOCKS) : (bid - CVT_BLOCKS - T1_BLOCKS);
        const int TX = isW1 ? (H1DIM / 32) : (OUT_C / 32);
        const int R  = isW1 ? IN_C : H1DIM;
        const int C  = isW1 ? H1DIM : OUT_C;
        const float* src = isW1 ? W1 : W2;
        bf16* dst = isW1 ? W1t : W2t;
        const int bc = (lb % TX) * 32;
        const int br = (lb / TX) * 32;
        const int tx = tid & 31, ty = tid >> 5;
        #pragma unroll
        for (int i = ty; i < 32; i += 8)
            tile[i][tx] = src[(size_t)(br + i) * C + bc + tx];
        __syncthreads();
        #pragma unroll
        for (int i = ty; i < 32; i += 8)
            dst[(size_t)(bc + i) * R + br + tx] = __float2bfloat16(tile[tx][i]);
        return;
    }
    const int i = (bid - CVT_BLOCKS - T1_BLOCKS - T2_BLOCKS) * 256 + tid;
    if (i < Z_WORDS) zbase[i] = 0;
}

// ---------------- CSR build ----------------
__global__ void count_deg(const int* __restrict__ ei, int* __restrict__ deg_d, int* __restrict__ deg_s) {
    const int e = blockIdx.x * blockDim.x + threadIdx.x;
    if (e >= N_EDGES) return;
    atomicAdd(&deg_d[ei[N_EDGES + e]], 1);
    atomicAdd(&deg_s[ei[e]], 1);
}

__global__ __launch_bounds__(1024) void scan_fast2(const int* __restrict__ deg_d, int* __restrict__ offs_d,
                                                   const int* __restrict__ deg_s, int* __restrict__ offs_s,
                                                   int n) {
    const int* deg = blockIdx.x ? deg_s : deg_d;
    int* offs      = blockIdx.x ? offs_s : offs_d;
    const int t = threadIdx.x;
    const int iter = (n + 1023) >> 10;
    const int base = t * iter;
    int ex[16];
    int sum = 0;
    for (int j = 0; j < iter; ++j) {
        const int i = base + j;
        const int v = (i < n) ? deg[i] : 0;
        ex[j] = sum;
        sum += v;
    }
    const int lane = t & 63, w = t >> 6;
    int inc = sum;
    #pragma unroll
    for (int o = 1; o < 64; o <<= 1) {
        const int x = __shfl_up(inc, o);
        if (lane >= o) inc += x;
    }
    __shared__ int wtot[16];
    if (lane == 63) wtot[w] = inc;
    __syncthreads();
    if (t == 0) {
        int c = 0;
        #pragma unroll
        for (int i = 0; i < 16; ++i) { const int x = wtot[i]; wtot[i] = c; c += x; }
    }
    __syncthreads();
    const int tbase = wtot[w] + inc - sum;
    for (int j = 0; j < iter; ++j) {
        const int i = base + j;
        if (i < n) offs[i] = tbase + ex[j];
    }
    if (t == 1023) offs[n] = tbase + sum;
}

__global__ void fill_csr(const int* __restrict__ ei,
                         const int* __restrict__ offs_d, const int* __restrict__ offs_s,
                         int* __restrict__ cur_d, int* __restrict__ cur_s,
                         int* __restrict__ eid_d, int* __restrict__ eid_s) {
    const int e = blockIdx.x * blockDim.x + threadIdx.x;
    if (e >= N_EDGES) return;
    const int d = ei[N_EDGES + e];
    const int p = atomicAdd(&cur_d[d], 1);
    eid_d[offs_d[d] + p] = e;
    const int s = ei[e];
    const int q = atomicAdd(&cur_s[s], 1);
    eid_s[offs_s[s] + q] = e;
}

// ---------------- MFMA NT GEMM, 128x64 tile (r15 proven — layer 2) ----------------
__global__ __launch_bounds__(256) void gemm_mfma64(const bf16* __restrict__ A,
                                                   const bf16* __restrict__ Bt,
                                                   bf16* __restrict__ C,
                                                   int M, int N, int K) {
    __shared__ short lds_a[128 * 5 * 8];
    __shared__ short lds_b[64 * 5 * 8];
    const int bm = blockIdx.y * 128;
    const int bn = blockIdx.x * 64;
    const int t = threadIdx.x;
    const int lane = t & 63;
    const int wv = t >> 6;
    const int fm = lane & 15;
    const int fq = lane >> 4;

    const short* ap0 = lds_a + ((wv * 32 + fm) * 5 + fq) * 8;
    const short* ap1 = ap0 + 16 * 5 * 8;
    const short* bp0 = lds_b + ((fm) * 5 + fq) * 8;
    const short* bp1 = bp0 + 16 * 5 * 8;
    const short* bp2 = bp0 + 32 * 5 * 8;
    const short* bp3 = bp0 + 48 * 5 * 8;

    const int srow = t >> 2;
    const int sseg = t & 3;
    short* sa0 = lds_a + (srow * 5 + sseg) * 8;
    short* sa1 = lds_a + ((srow + 64) * 5 + sseg) * 8;
    short* sb  = lds_b + (srow * 5 + sseg) * 8;
    const bool ok0 = (bm + srow) < M;
    const bool ok1 = (bm + 64 + srow) < M;
    const bf16* gA0 = A + (size_t)(bm + srow) * K + sseg * 8;
    const bf16* gA1 = A + (size_t)(bm + 64 + srow) * K + sseg * 8;
    const bf16* gB  = Bt + (size_t)(bn + srow) * K + sseg * 8;

    f32x4 acc[2][4];
    #pragma unroll
    for (int i = 0; i < 2; ++i)
        #pragma unroll
        for (int j = 0; j < 4; ++j) acc[i][j] = (f32x4){0.f, 0.f, 0.f, 0.f};

    uint4 av0 = {0u, 0u, 0u, 0u}, av1 = {0u, 0u, 0u, 0u};
    if (ok0) av0 = *(const uint4*)gA0;
    if (ok1) av1 = *(const uint4*)gA1;
    uint4 bv = *(const uint4*)gB;

    for (int k0 = 0; k0 < K; k0 += 32) {
        __syncthreads();
        *(uint4*)sa0 = av0;
        *(uint4*)sa1 = av1;
        *(uint4*)sb  = bv;
        __syncthreads();
        if (k0 + 32 < K) {
            if (ok0) av0 = *(const uint4*)(gA0 + k0 + 32);
            if (ok1) av1 = *(const uint4*)(gA1 + k0 + 32);
            bv = *(const uint4*)(gB + k0 + 32);
        }
        const bf16x8 a0 = *(const bf16x8*)ap0;
        const bf16x8 a1 = *(const bf16x8*)ap1;
        const bf16x8 b0 = *(const bf16x8*)bp0;
        const bf16x8 b1 = *(const bf16x8*)bp1;
        const bf16x8 b2 = *(const bf16x8*)bp2;
        const bf16x8 b3 = *(const bf16x8*)bp3;
        acc[0][0] = __builtin_amdgcn_mfma_f32_16x16x32_bf16(a0, b0, acc[0][0], 0, 0, 0);
        acc[0][1] = __builtin_amdgcn_mfma_f32_16x16x32_bf16(a0, b1, acc[0][1], 0, 0, 0);
        acc[0][2] = __builtin_amdgcn_mfma_f32_16x16x32_bf16(a0, b2, acc[0][2], 0, 0, 0);
        acc[0][3] = __builtin_amdgcn_mfma_f32_16x16x32_bf16(a0, b3, acc[0][3], 0, 0, 0);
        acc[1][0] = __builtin_amdgcn_mfma_f32_16x16x32_bf16(a1, b0, acc[1][0], 0, 0, 0);
        acc[1][1] = __builtin_amdgcn_mfma_f32_16x16x32_bf16(a1, b1, acc[1][1], 0, 0, 0);
        acc[1][2] = __builtin_amdgcn_mfma_f32_16x16x32_bf16(a1, b2, acc[1][2], 0, 0, 0);
        acc[1][3] = __builtin_amdgcn_mfma_f32_16x16x32_bf16(a1, b3, acc[1][3], 0, 0, 0);
    }

    #pragma unroll
    for (int i = 0; i < 2; ++i) {
        const int rb = bm + wv * 32 + i * 16 + fq * 4;
        #pragma unroll
        for (int r = 0; r < 4; ++r) {
            const int row = rb + r;
            if (row < M) {
                #pragma unroll
                for (int j = 0; j < 4; ++j)
                    C[(size_t)row * N + bn + j * 16 + fm] = __float2bfloat16(acc[i][j][r]);
            }
        }
    }
}

// ---------------- MFMA NT GEMM, 128x256 tile + fused attention-dot epilogue ---------
// Layer 1 only: N=1024, bn = blockIdx.x*256 -> each block owns exactly one head's
// full channel range for its 128 rows => per-row dots computed from fp32 accs,
// 16-lane shfl reduce, EXCLUSIVE (non-atomic) stores to a_s/a_d.
__global__ __launch_bounds__(256) void gemm_mfma256d(const bf16* __restrict__ A,
                                                     const bf16* __restrict__ Bt,
                                                     bf16* __restrict__ C,
                                                     const float* __restrict__ att_s,
                                                     const float* __restrict__ att_d,
                                                     float* __restrict__ a_s,
                                                     float* __restrict__ a_d,
                                                     int M, int N, int K) {
    __shared__ short lds_a[128 * 5 * 8];   // 10 KB
    __shared__ short lds_b[256 * 5 * 8];   // 20 KB
    const int bm = blockIdx.y * 128;
    const int bn = blockIdx.x * 256;
    const int head = bn >> 8;
    const int t = threadIdx.x;
    const int lane = t & 63;
    const int wv = t >> 6;                 // wave -> rows [wv*32, wv*32+32)
    const int fm = lane & 15;
    const int fq = lane >> 4;

    const short* ap0 = lds_a + ((wv * 32 + fm) * 5 + fq) * 8;
    const short* ap1 = ap0 + 16 * 5 * 8;

    const int srow = t >> 2;               // 0..63
    const int sseg = t & 3;
    short* sa0 = lds_a + (srow * 5 + sseg) * 8;
    short* sa1 = lds_a + ((srow + 64) * 5 + sseg) * 8;
    short* sb0 = lds_b + (srow * 5 + sseg) * 8;
    short* sb1 = lds_b + ((srow + 64) * 5 + sseg) * 8;
    short* sb2 = lds_b + ((srow + 128) * 5 + sseg) * 8;
    short* sb3 = lds_b + ((srow + 192) * 5 + sseg) * 8;
    const bool ok0 = (bm + srow) < M;
    const bool ok1 = (bm + 64 + srow) < M;
    const bf16* gA0 = A + (size_t)(bm + srow) * K + sseg * 8;
    const bf16* gA1 = A + (size_t)(bm + 64 + srow) * K + sseg * 8;
    const bf16* gB0 = Bt + (size_t)(bn + srow) * K + sseg * 8;
    const bf16* gB1 = Bt + (size_t)(bn + 64 + srow) * K + sseg * 8;
    const bf16* gB2 = Bt + (size_t)(bn + 128 + srow) * K + sseg * 8;
    const bf16* gB3 = Bt + (size_t)(bn + 192 + srow) * K + sseg * 8;

    f32x4 acc[2][16];
    #pragma unroll
    for (int i = 0; i < 2; ++i)
        #pragma unroll
        for (int j = 0; j < 16; ++j) acc[i][j] = (f32x4){0.f, 0.f, 0.f, 0.f};

    uint4 av0 = {0u, 0u, 0u, 0u}, av1 = {0u, 0u, 0u, 0u};
    if (ok0) av0 = *(const uint4*)gA0;
    if (ok1) av1 = *(const uint4*)gA1;
    uint4 bv0 = *(const uint4*)gB0;
    uint4 bv1 = *(const uint4*)gB1;
    uint4 bv2 = *(const uint4*)gB2;
    uint4 bv3 = *(const uint4*)gB3;

    for (int k0 = 0; k0 < K; k0 += 32) {
        __syncthreads();
        *(uint4*)sa0 = av0;
        *(uint4*)sa1 = av1;
        *(uint4*)sb0 = bv0;
        *(uint4*)sb1 = bv1;
        *(uint4*)sb2 = bv2;
        *(uint4*)sb3 = bv3;
        __syncthreads();
        if (k0 + 32 < K) {
            if (ok0) av0 = *(const uint4*)(gA0 + k0 + 32);
            if (ok1) av1 = *(const uint4*)(gA1 + k0 + 32);
            bv0 = *(const uint4*)(gB0 + k0 + 32);
            bv1 = *(const uint4*)(gB1 + k0 + 32);
            bv2 = *(const uint4*)(gB2 + k0 + 32);
            bv3 = *(const uint4*)(gB3 + k0 + 32);
        }
        const bf16x8 a0 = *(const bf16x8*)ap0;
        const bf16x8 a1 = *(const bf16x8*)ap1;
        #pragma unroll
        for (int j = 0; j < 16; ++j) {
            const bf16x8 bj = *(const bf16x8*)(lds_b + ((j * 16 + fm) * 5 + fq) * 8);
            acc[0][j] = __builtin_amdgcn_mfma_f32_16x16x32_bf16(a0, bj, acc[0][j], 0, 0, 0);
            acc[1][j] = __builtin_amdgcn_mfma_f32_16x16x32_bf16(a1, bj, acc[1][j], 0, 0, 0);
        }
    }

    // C store (C/D: col = lane&15, row = (lane>>4)*4 + reg per 16x16 tile)
    #pragma unroll
    for (int i = 0; i < 2; ++i) {
        const int rb = bm + wv * 32 + i * 16 + fq * 4;
        #pragma unroll
        for (int r = 0; r < 4; ++r) {
            const int row = rb + r;
            if (row < M) {
                #pragma unroll
                for (int j = 0; j < 16; ++j)
                    C[(size_t)row * N + bn + j * 16 + fm] = __float2bfloat16(acc[i][j][r]);
            }
        }
    }

    // fused dots: this block owns (rows, head) exclusively -> plain stores.
    #pragma unroll
    for (int i = 0; i < 2; ++i) {
        float ps[4] = {0.f, 0.f, 0.f, 0.f};
        float pd[4] = {0.f, 0.f, 0.f, 0.f};
        #pragma unroll
        for (int j = 0; j < 16; ++j) {
            const int col = bn + j * 16 + fm;
            const float sa_ = att_s[col];
            const float da_ = att_d[col];
            #pragma unroll
            for (int r = 0; r < 4; ++r) {
                ps[r] += acc[i][j][r] * sa_;
                pd[r] += acc[i][j][r] * da_;
            }
        }
        #pragma unroll
        for (int o = 1; o < 16; o <<= 1) {
            #pragma unroll
            for (int r = 0; r < 4; ++r) {
                ps[r] += __shfl_xor(ps[r], o);
                pd[r] += __shfl_xor(pd[r], o);
            }
        }
        if (fm == 0) {
            const int rb = bm + wv * 32 + i * 16 + fq * 4;
            #pragma unroll
            for (int r = 0; r < 4; ++r) {
                const int row = rb + r;
                if (row < M) {
                    a_s[row * HEADS + head] = ps[r];
                    a_d[row * HEADS + head] = pd[r];
                }
            }
        }
    }
}

// ---------------- attention dots (layer 2 only) ----------------
__global__ __launch_bounds__(256) void att_dots(const bf16* __restrict__ h,
                                                const float* __restrict__ ws_,
                                                const float* __restrict__ wd_,
                                                float* __restrict__ a_s,
                                                float* __restrict__ a_d,
                                                int rows, int heads) {
    const int r = blockIdx.x * 4 + (threadIdx.x >> 6);
    if (r >= rows) return;
    const int lane = threadIdx.x & 63;
    const int hd = r % heads;
    const ushort4 hv = *(const ushort4*)(h + (size_t)r * 256 + lane * 4);
    const float4 sv = *(const float4*)(ws_ + hd * 256 + lane * 4);
    const float4 dv = *(const float4*)(wd_ + hd * 256 + lane * 4);
    const float v0 = u2f(hv.x), v1 = u2f(hv.y), v2 = u2f(hv.z), v3 = u2f(hv.w);
    float ss = v0 * sv.x + v1 * sv.y + v2 * sv.z + v3 * sv.w;
    float sd = v0 * dv.x + v1 * dv.y + v2 * dv.z + v3 * dv.w;
    #pragma unroll
    for (int o = 32; o > 0; o >>= 1) {
        ss += __shfl_xor(ss, o);
        sd += __shfl_xor(sd, o);
    }
    if (lane == 0) { a_s[r] = ss; a_d[r] = sd; }
}

// ---------------- layer 1: per-node softmax + gather + bias + ELU (r11 proven) -------
__global__ __launch_bounds__(256) void gat_gather1(
    const int* __restrict__ ei, const int* __restrict__ offs, const int* __restrict__ eid,
    const bf16* __restrict__ h1, const float* __restrict__ a_s, const float* __restrict__ a_d,
    const float* __restrict__ bias, bf16* __restrict__ outp)
{
    const int n = blockIdx.x;
    const int beg = offs[n];
    const int deg = offs[n + 1] - beg;
    const int t = threadIdx.x, lane = t & 63, wave = t >> 6;
    __shared__ float m_sh[HEADS], den_sh[HEADS];
    __shared__ float al_sh[64][HEADS];
    __shared__ int   src_sh[64];

    if (wave == 0 && deg > 0) {
        float adv[HEADS];
        #pragma unroll
        for (int h = 0; h < HEADS; ++h) adv[h] = a_d[n * HEADS + h];
        float mx[HEADS];
        #pragma unroll
        for (int h = 0; h < HEADS; ++h) mx[h] = -INFINITY;
        for (int k = lane; k < deg; k += 64) {
            const int s = ei[eid[beg + k]];
            #pragma unroll
            for (int h = 0; h < HEADS; ++h) {
                float v = a_s[s * HEADS + h] + adv[h];
                v = v > 0.f ? v : NEG_SLOPE * v;
                mx[h] = fmaxf(mx[h], v);
            }
        }
        #pragma unroll
        for (int o = 32; o > 0; o >>= 1)
            #pragma unroll
            for (int h = 0; h < HEADS; ++h) mx[h] = fmaxf(mx[h], __shfl_xor(mx[h], o));
        float sm[HEADS] = {0.f, 0.f, 0.f, 0.f};
        for (int k = lane; k < deg; k += 64) {
            const int s = ei[eid[beg + k]];
            #pragma unroll
            for (int h = 0; h < HEADS; ++h) {
                float v = a_s[s * HEADS + h] + adv[h];
                v = v > 0.f ? v : NEG_SLOPE * v;
                sm[h] += __expf(v - mx[h]);
            }
        }
        #pragma unroll
        for (int o = 32; o > 0; o >>= 1)
            #pragma unroll
            for (int h = 0; h < HEADS; ++h) sm[h] += __shfl_xor(sm[h], o);
        if (lane == 0) {
            #pragma unroll
            for (int h = 0; h < HEADS; ++h) { m_sh[h] = mx[h]; den_sh[h] = sm[h] + 1e-16f; }
        }
    }
    __syncthreads();

    float acc0 = 0.f, acc1 = 0.f, acc2 = 0.f, acc3 = 0.f;
    const int myh = t >> 6;
    for (int bs = 0; bs < deg; bs += 64) {
        const int cnt = min(64, deg - bs);
        if (wave == 0 && lane < cnt) {
            const int e = eid[beg + bs + lane];
            const int s = ei[e];
            src_sh[lane] = s;
            #pragma unroll
            for (int h = 0; h < HEADS; ++h) {
                float v = a_s[s * HEADS + h] + a_d[n * HEADS + h];
                v = v > 0.f ? v : NEG_SLOPE * v;
                al_sh[lane][h] = __expf(v - m_sh[h]) / den_sh[h];
            }
        }
        __syncthreads();
        for (int k = 0; k < cnt; ++k) {
            const int s = src_sh[k];
            const float al = al_sh[k][myh];
            const ushort4 hv = *((const ushort4*)(h1 + (size_t)s * H1DIM) + t);
            acc0 += u2f(hv.x) * al; acc1 += u2f(hv.y) * al;
            acc2 += u2f(hv.z) * al; acc3 += u2f(hv.w) * al;
        }
        __syncthreads();
    }
    float v0 = acc0 + bias[t * 4 + 0];
    float v1 = acc1 + bias[t * 4 + 1];
    float v2 = acc2 + bias[t * 4 + 2];
    float v3 = acc3 + bias[t * 4 + 3];
    v0 = v0 > 0.f ? v0 : expm1f(v0);
    v1 = v1 > 0.f ? v1 : expm1f(v1);
    v2 = v2 > 0.f ? v2 : expm1f(v2);
    v3 = v3 > 0.f ? v3 : expm1f(v3);
    bf16* op = outp + (size_t)n * H1DIM + t * 4;
    op[0] = __float2bfloat16(v0); op[1] = __float2bfloat16(v1);
    op[2] = __float2bfloat16(v2); op[3] = __float2bfloat16(v3);
}

// ---------------- layer 2: softmax + gather (16B/lane, 8 edges in flight), fp32 out --
__global__ __launch_bounds__(256) void gat_gather2(
    const int* __restrict__ ei, const int* __restrict__ offs, const int* __restrict__ eid,
    const bf16* __restrict__ h2, const float* __restrict__ a_s, const float* __restrict__ a_d,
    const float* __restrict__ bias, float* __restrict__ outp)
{
    const int n = blockIdx.x;
    const int beg = offs[n];
    const int deg = offs[n + 1] - beg;
    const int t = threadIdx.x, lane = t & 63, wave = t >> 6;
    __shared__ float m_sh, den_sh;
    __shared__ float al_sh[64];
    __shared__ int   src_sh[64];
    __shared__ float red[8][32][8];

    if (wave == 0 && deg > 0) {
        const float adn = a_d[n];
        float mx = -INFINITY;
        for (int k = lane; k < deg; k += 64) {
            const int s = ei[N_EDGES + eid[beg + k]];
            float v = a_s[s] + adn;
            v = v > 0.f ? v : NEG_SLOPE * v;
            mx = fmaxf(mx, v);
        }
        #pragma unroll
        for (int o = 32; o > 0; o >>= 1) mx = fmaxf(mx, __shfl_xor(mx, o));
        float sm = 0.f;
        for (int k = lane; k < deg; k += 64) {
            const int s = ei[N_EDGES + eid[beg + k]];
            float v = a_s[s] + adn;
            v = v > 0.f ? v : NEG_SLOPE * v;
            sm += __expf(v - mx);
        }
        #pragma unroll
        for (int o = 32; o > 0; o >>= 1) sm += __shfl_xor(sm, o);
        if (lane == 0) { m_sh = mx; den_sh = sm + 1e-16f; }
    }
    __syncthreads();

    const int g = t >> 5;
    const int l32 = t & 31;
    const int ch = l32 * 8;
    float acc[8] = {0.f, 0.f, 0.f, 0.f, 0.f, 0.f, 0.f, 0.f};

    for (int bs = 0; bs < deg; bs += 64) {
        const int cnt = min(64, deg - bs);
        if (wave == 0 && lane < cnt) {
            const int e = eid[beg + bs + lane];
            const int s = ei[N_EDGES + e];
            src_sh[lane] = s;
            float v = a_s[s] + a_d[n];
            v = v > 0.f ? v : NEG_SLOPE * v;
            al_sh[lane] = __expf(v - m_sh) / den_sh;
        }
        __syncthreads();
        for (int k = 0; k < cnt; k += 8) {
            const int kk = k + g;
            if (kk < cnt) {
                const int s = src_sh[kk];
                const float al = al_sh[kk];
                const uint4 hv = *(const uint4*)(h2 + (size_t)s * OUT_C + ch);
                acc[0] += lo2f(hv.x) * al; acc[1] += hi2f(hv.x) * al;
                acc[2] += lo2f(hv.y) * al; acc[3] += hi2f(hv.y) * al;
                acc[4] += lo2f(hv.z) * al; acc[5] += hi2f(hv.z) * al;
                acc[6] += lo2f(hv.w) * al; acc[7] += hi2f(hv.w) * al;
            }
        }
        __syncthreads();
    }

    #pragma unroll
    for (int j = 0; j < 8; ++j) red[g][l32][j] = acc[j];
    __syncthreads();
    if (g == 0) {
        #pragma unroll
        for (int gg = 1; gg < 8; ++gg)
            #pragma unroll
            for (int j = 0; j < 8; ++j) acc[j] += red[gg][l32][j];
        float4 w0, w1;
        w0.x = acc[0] + bias[ch + 0]; w0.y = acc[1] + bias[ch + 1];
        w0.z = acc[2] + bias[ch + 2]; w0.w = acc[3] + bias[ch + 3];
        w1.x = acc[4] + bias[ch + 4]; w1.y = acc[5] + bias[ch + 5];
        w1.z = acc[6] + bias[ch + 6]; w1.w = acc[7] + bias[ch + 7];
        *(float4*)(outp + (size_t)n * OUT_C + ch)     = w0;
        *(float4*)(outp + (size_t)n * OUT_C + ch + 4) = w1;
    }
}

extern "C" void kernel_launch(void* const* d_in, const int* in_sizes, int n_in,
                              void* d_out, int out_size, void* d_ws, size_t ws_size,
                              hipStream_t stream) {
    (void)in_sizes; (void)n_in; (void)out_size; (void)ws_size;
    const float* x        = (const float*)d_in[0];
    const int*   ei       = (const int*)d_in[1];   // int32 [2,E] (verified round 4)
    const float* W1       = (const float*)d_in[2];
    const float* att_src1 = (const float*)d_in[3];
    const float* att_dst1 = (const float*)d_in[4];
    const float* b1       = (const float*)d_in[5];
    const float* W2       = (const float*)d_in[6];
    const float* att_src2 = (const float*)d_in[7];
    const float* att_dst2 = (const float*)d_in[8];
    const float* b2       = (const float*)d_in[9];
    float* out = (float*)d_out;

    // ---- workspace carve (all 256B-aligned) ----
    char* base = (char*)d_ws;
    size_t woff = 0;
    auto carve = [&](size_t bytes) -> char* {
        char* p = base + woff;
        woff += (bytes + 255) & ~(size_t)255;
        return p;
    };
    bf16* h1   = (bf16*)carve((size_t)N_NODES * H1DIM * 2);   // 20.48 MB
    bf16* a2   = (bf16*)carve((size_t)N_NODES * H1DIM * 2);   // 20.48 MB
    bf16* h2   = (bf16*)carve((size_t)N_NODES * OUT_C * 2);   //  5.12 MB
    bf16* xb   = (bf16*)carve((size_t)N_NODES * IN_C * 2);    // 15.36 MB
    bf16* W1t  = (bf16*)carve((size_t)H1DIM * IN_C * 2);
    bf16* W2t  = (bf16*)carve((size_t)OUT_C * H1DIM * 2);
    // NOTE: as1..degs must stay CONTIGUOUS — prep_kernel zeroes the whole span.
    float* as1 = (float*)carve((size_t)N_NODES * HEADS * 4);  // 160000 B
    float* ad1 = (float*)carve((size_t)N_NODES * HEADS * 4);  // 160000 B
    float* as2 = (float*)carve((size_t)N_NODES * 4);          // 40000 -> 40192 B
    float* ad2 = (float*)carve((size_t)N_NODES * 4);          // 40000 -> 40192 B
    int* degs  = (int*)carve((size_t)4 * N_NODES * 4);        // 160000 B
    int* deg_d = degs;
    int* deg_s = degs + N_NODES;
    int* cur_d = degs + 2 * N_NODES;
    int* cur_s = degs + 3 * N_NODES;
    int* offs_d = (int*)carve((size_t)(N_NODES + 1) * 4);
    int* offs_s = (int*)carve((size_t)(N_NODES + 1) * 4);
    int* eid_d  = (int*)carve((size_t)N_EDGES * 4);
    int* eid_s  = (int*)carve((size_t)N_EDGES * 4);

    // ---- fused prep: cvt + transposes + zero(as1..degs) ----
    prep_kernel<<<CVT_BLOCKS + T1_BLOCKS + T2_BLOCKS + Z_BLOCKS, 256, 0, stream>>>(
        x, xb, W1, W1t, W2, W2t, (int*)as1);

    // ---- CSR build ----
    count_deg<<<(N_EDGES + 255) / 256, 256, 0, stream>>>(ei, deg_d, deg_s);
    scan_fast2<<<2, 1024, 0, stream>>>(deg_d, offs_d, deg_s, offs_s, N_NODES);
    fill_csr<<<(N_EDGES + 255) / 256, 256, 0, stream>>>(ei, offs_d, offs_s, cur_d, cur_s, eid_d, eid_s);

    // ---- layer 1 (128x256 gemm with fused attention dots; no separate dots pass) ----
    gemm_mfma256d<<<dim3(H1DIM / 256, (N_NODES + 127) / 128), 256, 0, stream>>>(
        xb, W1t, h1, att_src1, att_dst1, as1, ad1, N_NODES, H1DIM, IN_C);
    gat_gather1<<<N_NODES, 256, 0, stream>>>(ei, offs_d, eid_d, h1, as1, ad1, b1, a2);

    // ---- layer 2 (128x64 gemm + tiny dots) ----
    gemm_mfma64<<<dim3(OUT_C / 64, (N_NODES + 127) / 128), 256, 0, stream>>>(
        a2, W2t, h2, N_NODES, OUT_C, H1DIM);
    att_dots<<<(N_NODES + 3) / 4, 256, 0, stream>>>(
        h2, att_src2, att_dst2, as2, ad2, N_NODES, 1);
    gat_gather2<<<N_NODES, 256, 0, stream>>>(ei, offs_s, eid_s, h2, as2, ad2, b2, out);
}

// Round 19
// 279.191 us; speedup vs baseline: 1.0460x; 1.0460x over previous
//
#include <hip/hip_runtime.h>
#include <hip/hip_bf16.h>
#include <math.h>

typedef __hip_bfloat16 bf16;
typedef __attribute__((ext_vector_type(8))) short bf16x8;
typedef __attribute__((ext_vector_type(4))) float f32x4;

#define N_NODES 10000
#define N_EDGES 160000
#define IN_C    768
#define H1DIM   1024      // HEADS * HID
#define HEADS   4
#define OUT_C   256
#define NEG_SLOPE 0.2f

__device__ __forceinline__ float b2f(bf16 v) { return __bfloat162float(v); }
__device__ __forceinline__ float u2f(unsigned short u) { return __uint_as_float(((unsigned)u) << 16); }
__device__ __forceinline__ float lo2f(unsigned u) { return __uint_as_float(u << 16); }
__device__ __forceinline__ float hi2f(unsigned u) { return __uint_as_float(u & 0xFFFF0000u); }

// ---------------- fused prep: cvt x->bf16, transpose W1/W2, zero (r15 proven) -------
#define CVT_BLOCKS 7500                    // 10000*768/4 / 256  (exact)
#define T1_BLOCKS  768                     // (1024/32) x (768/32)
#define T2_BLOCKS  256                     // (256/32) x (1024/32)
#define Z_WORDS    140096                  // as1+ad1+as2+ad2+degs span (with carve pads)/4
#define Z_BLOCKS   548                     // ceil(Z_WORDS/256)

__global__ __launch_bounds__(256) void prep_kernel(
    const float* __restrict__ x, bf16* __restrict__ xb,
    const float* __restrict__ W1, bf16* __restrict__ W1t,
    const float* __restrict__ W2, bf16* __restrict__ W2t,
    int* __restrict__ zbase)
{
    __shared__ float tile[32][33];
    const int bid = blockIdx.x;
    const int tid = threadIdx.x;
    if (bid < CVT_BLOCKS) {
        const int i = bid * 256 + tid;
        const float4 v = *((const float4*)x + i);
        bf16* d = xb + (size_t)i * 4;
        d[0] = __float2bfloat16(v.x); d[1] = __float2bfloat16(v.y);
        d[2] = __float2bfloat16(v.z); d[3] = __float2bfloat16(v.w);
        return;
    }
    if (bid < CVT_BLOCKS + T1_BLOCKS + T2_BLOCKS) {
        const bool isW1 = bid < CVT_BLOCKS + T1_BLOCKS;
        const int lb = isW1 ? (bid - CVT_BLOCKS) : (bid - CVT_BLOCKS - T1_BLOCKS);
        const int TX = isW1 ? (H1DIM / 32) : (OUT_C / 32);
        const int R  = isW1 ? IN_C : H1DIM;      // src rows
        const int C  = isW1 ? H1DIM : OUT_C;     // src cols
        const float* src = isW1 ? W1 : W2;
        bf16* dst = isW1 ? W1t : W2t;
        const int bc = (lb % TX) * 32;
        const int br = (lb / TX) * 32;
        const int tx = tid & 31, ty = tid >> 5;
        #pragma unroll
        for (int i = ty; i < 32; i += 8)
            tile[i][tx] = src[(size_t)(br + i) * C + bc + tx];
        __syncthreads();
        #pragma unroll
        for (int i = ty; i < 32; i += 8)
            dst[(size_t)(bc + i) * R + br + tx] = __float2bfloat16(tile[tx][i]);
        return;
    }
    const int i = (bid - CVT_BLOCKS - T1_BLOCKS - T2_BLOCKS) * 256 + tid;
    if (i < Z_WORDS) zbase[i] = 0;
}

// ---------------- CSR build ----------------
__global__ void count_deg(const int* __restrict__ ei, int* __restrict__ deg_d, int* __restrict__ deg_s) {
    const int e = blockIdx.x * blockDim.x + threadIdx.x;
    if (e >= N_EDGES) return;
    atomicAdd(&deg_d[ei[N_EDGES + e]], 1);
    atomicAdd(&deg_s[ei[e]], 1);
}

__global__ __launch_bounds__(1024) void scan_fast2(const int* __restrict__ deg_d, int* __restrict__ offs_d,
                                                   const int* __restrict__ deg_s, int* __restrict__ offs_s,
                                                   int n) {
    const int* deg = blockIdx.x ? deg_s : deg_d;
    int* offs      = blockIdx.x ? offs_s : offs_d;
    const int t = threadIdx.x;
    const int iter = (n + 1023) >> 10;
    const int base = t * iter;
    int ex[16];
    int sum = 0;
    for (int j = 0; j < iter; ++j) {
        const int i = base + j;
        const int v = (i < n) ? deg[i] : 0;
        ex[j] = sum;
        sum += v;
    }
    const int lane = t & 63, w = t >> 6;
    int inc = sum;
    #pragma unroll
    for (int o = 1; o < 64; o <<= 1) {
        const int x = __shfl_up(inc, o);
        if (lane >= o) inc += x;
    }
    __shared__ int wtot[16];
    if (lane == 63) wtot[w] = inc;
    __syncthreads();
    if (t == 0) {
        int c = 0;
        #pragma unroll
        for (int i = 0; i < 16; ++i) { const int x = wtot[i]; wtot[i] = c; c += x; }
    }
    __syncthreads();
    const int tbase = wtot[w] + inc - sum;
    for (int j = 0; j < iter; ++j) {
        const int i = base + j;
        if (i < n) offs[i] = tbase + ex[j];
    }
    if (t == 1023) offs[n] = tbase + sum;
}

__global__ void fill_csr(const int* __restrict__ ei,
                         const int* __restrict__ offs_d, const int* __restrict__ offs_s,
                         int* __restrict__ cur_d, int* __restrict__ cur_s,
                         int* __restrict__ eid_d, int* __restrict__ eid_s) {
    const int e = blockIdx.x * blockDim.x + threadIdx.x;
    if (e >= N_EDGES) return;
    const int d = ei[N_EDGES + e];
    const int p = atomicAdd(&cur_d[d], 1);
    eid_d[offs_d[d] + p] = e;
    const int s = ei[e];
    const int q = atomicAdd(&cur_s[s], 1);
    eid_s[offs_s[s] + q] = e;
}

// ---------------- MFMA NT GEMM, 128x64 tile (r15 proven — layer 2) ----------------
__global__ __launch_bounds__(256) void gemm_mfma64(const bf16* __restrict__ A,
                                                   const bf16* __restrict__ Bt,
                                                   bf16* __restrict__ C,
                                                   int M, int N, int K) {
    __shared__ short lds_a[128 * 5 * 8];
    __shared__ short lds_b[64 * 5 * 8];
    const int bm = blockIdx.y * 128;
    const int bn = blockIdx.x * 64;
    const int t = threadIdx.x;
    const int lane = t & 63;
    const int wv = t >> 6;
    const int fm = lane & 15;
    const int fq = lane >> 4;

    const short* ap0 = lds_a + ((wv * 32 + fm) * 5 + fq) * 8;
    const short* ap1 = ap0 + 16 * 5 * 8;
    const short* bp0 = lds_b + ((fm) * 5 + fq) * 8;
    const short* bp1 = bp0 + 16 * 5 * 8;
    const short* bp2 = bp0 + 32 * 5 * 8;
    const short* bp3 = bp0 + 48 * 5 * 8;

    const int srow = t >> 2;
    const int sseg = t & 3;
    short* sa0 = lds_a + (srow * 5 + sseg) * 8;
    short* sa1 = lds_a + ((srow + 64) * 5 + sseg) * 8;
    short* sb  = lds_b + (srow * 5 + sseg) * 8;
    const bool ok0 = (bm + srow) < M;
    const bool ok1 = (bm + 64 + srow) < M;
    const bf16* gA0 = A + (size_t)(bm + srow) * K + sseg * 8;
    const bf16* gA1 = A + (size_t)(bm + 64 + srow) * K + sseg * 8;
    const bf16* gB  = Bt + (size_t)(bn + srow) * K + sseg * 8;

    f32x4 acc[2][4];
    #pragma unroll
    for (int i = 0; i < 2; ++i)
        #pragma unroll
        for (int j = 0; j < 4; ++j) acc[i][j] = (f32x4){0.f, 0.f, 0.f, 0.f};

    uint4 av0 = {0u, 0u, 0u, 0u}, av1 = {0u, 0u, 0u, 0u};
    if (ok0) av0 = *(const uint4*)gA0;
    if (ok1) av1 = *(const uint4*)gA1;
    uint4 bv = *(const uint4*)gB;

    for (int k0 = 0; k0 < K; k0 += 32) {
        __syncthreads();
        *(uint4*)sa0 = av0;
        *(uint4*)sa1 = av1;
        *(uint4*)sb  = bv;
        __syncthreads();
        if (k0 + 32 < K) {
            if (ok0) av0 = *(const uint4*)(gA0 + k0 + 32);
            if (ok1) av1 = *(const uint4*)(gA1 + k0 + 32);
            bv = *(const uint4*)(gB + k0 + 32);
        }
        const bf16x8 a0 = *(const bf16x8*)ap0;
        const bf16x8 a1 = *(const bf16x8*)ap1;
        const bf16x8 b0 = *(const bf16x8*)bp0;
        const bf16x8 b1 = *(const bf16x8*)bp1;
        const bf16x8 b2 = *(const bf16x8*)bp2;
        const bf16x8 b3 = *(const bf16x8*)bp3;
        acc[0][0] = __builtin_amdgcn_mfma_f32_16x16x32_bf16(a0, b0, acc[0][0], 0, 0, 0);
        acc[0][1] = __builtin_amdgcn_mfma_f32_16x16x32_bf16(a0, b1, acc[0][1], 0, 0, 0);
        acc[0][2] = __builtin_amdgcn_mfma_f32_16x16x32_bf16(a0, b2, acc[0][2], 0, 0, 0);
        acc[0][3] = __builtin_amdgcn_mfma_f32_16x16x32_bf16(a0, b3, acc[0][3], 0, 0, 0);
        acc[1][0] = __builtin_amdgcn_mfma_f32_16x16x32_bf16(a1, b0, acc[1][0], 0, 0, 0);
        acc[1][1] = __builtin_amdgcn_mfma_f32_16x16x32_bf16(a1, b1, acc[1][1], 0, 0, 0);
        acc[1][2] = __builtin_amdgcn_mfma_f32_16x16x32_bf16(a1, b2, acc[1][2], 0, 0, 0);
        acc[1][3] = __builtin_amdgcn_mfma_f32_16x16x32_bf16(a1, b3, acc[1][3], 0, 0, 0);
    }

    #pragma unroll
    for (int i = 0; i < 2; ++i) {
        const int rb = bm + wv * 32 + i * 16 + fq * 4;
        #pragma unroll
        for (int r = 0; r < 4; ++r) {
            const int row = rb + r;
            if (row < M) {
                #pragma unroll
                for (int j = 0; j < 4; ++j)
                    C[(size_t)row * N + bn + j * 16 + fm] = __float2bfloat16(acc[i][j][r]);
            }
        }
    }
}

// ---------------- MFMA NT GEMM, 128x128 tile (r17 proven — layer 1) ----------------
__global__ __launch_bounds__(256) void gemm_mfma128(const bf16* __restrict__ A,
                                                    const bf16* __restrict__ Bt,
                                                    bf16* __restrict__ C,
                                                    int M, int N, int K) {
    __shared__ short lds_a[128 * 5 * 8];   // 10 KB
    __shared__ short lds_b[128 * 5 * 8];   // 10 KB
    const int bm = blockIdx.y * 128;
    const int bn = blockIdx.x * 128;
    const int t = threadIdx.x;
    const int lane = t & 63;
    const int wv = t >> 6;                 // wave -> rows [wv*32, wv*32+32)
    const int fm = lane & 15;
    const int fq = lane >> 4;

    const short* ap0 = lds_a + ((wv * 32 + fm) * 5 + fq) * 8;
    const short* ap1 = ap0 + 16 * 5 * 8;

    const int srow = t >> 2;               // 0..63
    const int sseg = t & 3;
    short* sa0 = lds_a + (srow * 5 + sseg) * 8;
    short* sa1 = lds_a + ((srow + 64) * 5 + sseg) * 8;
    short* sb0 = lds_b + (srow * 5 + sseg) * 8;
    short* sb1 = lds_b + ((srow + 64) * 5 + sseg) * 8;
    const bool ok0 = (bm + srow) < M;
    const bool ok1 = (bm + 64 + srow) < M;
    const bf16* gA0 = A + (size_t)(bm + srow) * K + sseg * 8;
    const bf16* gA1 = A + (size_t)(bm + 64 + srow) * K + sseg * 8;
    const bf16* gB0 = Bt + (size_t)(bn + srow) * K + sseg * 8;
    const bf16* gB1 = Bt + (size_t)(bn + 64 + srow) * K + sseg * 8;

    f32x4 acc[2][8];
    #pragma unroll
    for (int i = 0; i < 2; ++i)
        #pragma unroll
        for (int j = 0; j < 8; ++j) acc[i][j] = (f32x4){0.f, 0.f, 0.f, 0.f};

    uint4 av0 = {0u, 0u, 0u, 0u}, av1 = {0u, 0u, 0u, 0u};
    if (ok0) av0 = *(const uint4*)gA0;
    if (ok1) av1 = *(const uint4*)gA1;
    uint4 bv0 = *(const uint4*)gB0;
    uint4 bv1 = *(const uint4*)gB1;

    for (int k0 = 0; k0 < K; k0 += 32) {
        __syncthreads();
        *(uint4*)sa0 = av0;
        *(uint4*)sa1 = av1;
        *(uint4*)sb0 = bv0;
        *(uint4*)sb1 = bv1;
        __syncthreads();
        if (k0 + 32 < K) {
            if (ok0) av0 = *(const uint4*)(gA0 + k0 + 32);
            if (ok1) av1 = *(const uint4*)(gA1 + k0 + 32);
            bv0 = *(const uint4*)(gB0 + k0 + 32);
            bv1 = *(const uint4*)(gB1 + k0 + 32);
        }
        const bf16x8 a0 = *(const bf16x8*)ap0;
        const bf16x8 a1 = *(const bf16x8*)ap1;
        #pragma unroll
        for (int j = 0; j < 8; ++j) {
            const bf16x8 bj = *(const bf16x8*)(lds_b + ((j * 16 + fm) * 5 + fq) * 8);
            acc[0][j] = __builtin_amdgcn_mfma_f32_16x16x32_bf16(a0, bj, acc[0][j], 0, 0, 0);
            acc[1][j] = __builtin_amdgcn_mfma_f32_16x16x32_bf16(a1, bj, acc[1][j], 0, 0, 0);
        }
    }

    // C/D layout: col = lane&15, row = (lane>>4)*4 + reg (per 16x16 tile)
    #pragma unroll
    for (int i = 0; i < 2; ++i) {
        const int rb = bm + wv * 32 + i * 16 + fq * 4;
        #pragma unroll
        for (int r = 0; r < 4; ++r) {
            const int row = rb + r;
            if (row < M) {
                #pragma unroll
                for (int j = 0; j < 8; ++j)
                    C[(size_t)row * N + bn + j * 16 + fm] = __float2bfloat16(acc[i][j][r]);
            }
        }
    }
}

// ---------------- attention dots: one wave per row of 256, vectorized ----------------
__global__ __launch_bounds__(256) void att_dots(const bf16* __restrict__ h,
                                                const float* __restrict__ ws_,
                                                const float* __restrict__ wd_,
                                                float* __restrict__ a_s,
                                                float* __restrict__ a_d,
                                                int rows, int heads) {
    const int r = blockIdx.x * 4 + (threadIdx.x >> 6);
    if (r >= rows) return;
    const int lane = threadIdx.x & 63;
    const int hd = r % heads;
    const ushort4 hv = *(const ushort4*)(h + (size_t)r * 256 + lane * 4);
    const float4 sv = *(const float4*)(ws_ + hd * 256 + lane * 4);
    const float4 dv = *(const float4*)(wd_ + hd * 256 + lane * 4);
    const float v0 = u2f(hv.x), v1 = u2f(hv.y), v2 = u2f(hv.z), v3 = u2f(hv.w);
    float ss = v0 * sv.x + v1 * sv.y + v2 * sv.z + v3 * sv.w;
    float sd = v0 * dv.x + v1 * dv.y + v2 * dv.z + v3 * dv.w;
    #pragma unroll
    for (int o = 32; o > 0; o >>= 1) {
        ss += __shfl_xor(ss, o);
        sd += __shfl_xor(sd, o);
    }
    if (lane == 0) { a_s[r] = ss; a_d[r] = sd; }
}

// ---------------- layer 1: per-node softmax + gather + bias + ELU (r11 proven) -------
__global__ __launch_bounds__(256) void gat_gather1(
    const int* __restrict__ ei, const int* __restrict__ offs, const int* __restrict__ eid,
    const bf16* __restrict__ h1, const float* __restrict__ a_s, const float* __restrict__ a_d,
    const float* __restrict__ bias, bf16* __restrict__ outp)
{
    const int n = blockIdx.x;
    const int beg = offs[n];
    const int deg = offs[n + 1] - beg;
    const int t = threadIdx.x, lane = t & 63, wave = t >> 6;
    __shared__ float m_sh[HEADS], den_sh[HEADS];
    __shared__ float al_sh[64][HEADS];
    __shared__ int   src_sh[64];

    if (wave == 0 && deg > 0) {
        float adv[HEADS];
        #pragma unroll
        for (int h = 0; h < HEADS; ++h) adv[h] = a_d[n * HEADS + h];
        float mx[HEADS];
        #pragma unroll
        for (int h = 0; h < HEADS; ++h) mx[h] = -INFINITY;
        for (int k = lane; k < deg; k += 64) {
            const int s = ei[eid[beg + k]];
            #pragma unroll
            for (int h = 0; h < HEADS; ++h) {
                float v = a_s[s * HEADS + h] + adv[h];
                v = v > 0.f ? v : NEG_SLOPE * v;
                mx[h] = fmaxf(mx[h], v);
            }
        }
        #pragma unroll
        for (int o = 32; o > 0; o >>= 1)
            #pragma unroll
            for (int h = 0; h < HEADS; ++h) mx[h] = fmaxf(mx[h], __shfl_xor(mx[h], o));
        float sm[HEADS] = {0.f, 0.f, 0.f, 0.f};
        for (int k = lane; k < deg; k += 64) {
            const int s = ei[eid[beg + k]];
            #pragma unroll
            for (int h = 0; h < HEADS; ++h) {
                float v = a_s[s * HEADS + h] + adv[h];
                v = v > 0.f ? v : NEG_SLOPE * v;
                sm[h] += __expf(v - mx[h]);
            }
        }
        #pragma unroll
        for (int o = 32; o > 0; o >>= 1)
            #pragma unroll
            for (int h = 0; h < HEADS; ++h) sm[h] += __shfl_xor(sm[h], o);
        if (lane == 0) {
            #pragma unroll
            for (int h = 0; h < HEADS; ++h) { m_sh[h] = mx[h]; den_sh[h] = sm[h] + 1e-16f; }
        }
    }
    __syncthreads();

    float acc0 = 0.f, acc1 = 0.f, acc2 = 0.f, acc3 = 0.f;
    const int myh = t >> 6;
    for (int bs = 0; bs < deg; bs += 64) {
        const int cnt = min(64, deg - bs);
        if (wave == 0 && lane < cnt) {
            const int e = eid[beg + bs + lane];
            const int s = ei[e];
            src_sh[lane] = s;
            #pragma unroll
            for (int h = 0; h < HEADS; ++h) {
                float v = a_s[s * HEADS + h] + a_d[n * HEADS + h];
                v = v > 0.f ? v : NEG_SLOPE * v;
                al_sh[lane][h] = __expf(v - m_sh[h]) / den_sh[h];
            }
        }
        __syncthreads();
        for (int k = 0; k < cnt; ++k) {
            const int s = src_sh[k];
            const float al = al_sh[k][myh];
            const ushort4 hv = *((const ushort4*)(h1 + (size_t)s * H1DIM) + t);
            acc0 += u2f(hv.x) * al; acc1 += u2f(hv.y) * al;
            acc2 += u2f(hv.z) * al; acc3 += u2f(hv.w) * al;
        }
        __syncthreads();
    }
    float v0 = acc0 + bias[t * 4 + 0];
    float v1 = acc1 + bias[t * 4 + 1];
    float v2 = acc2 + bias[t * 4 + 2];
    float v3 = acc3 + bias[t * 4 + 3];
    v0 = v0 > 0.f ? v0 : expm1f(v0);
    v1 = v1 > 0.f ? v1 : expm1f(v1);
    v2 = v2 > 0.f ? v2 : expm1f(v2);
    v3 = v3 > 0.f ? v3 : expm1f(v3);
    bf16* op = outp + (size_t)n * H1DIM + t * 4;
    op[0] = __float2bfloat16(v0); op[1] = __float2bfloat16(v1);
    op[2] = __float2bfloat16(v2); op[3] = __float2bfloat16(v3);
}

// ---------------- layer 2: softmax + gather (16B/lane, 8 edges in flight), fp32 out --
__global__ __launch_bounds__(256) void gat_gather2(
    const int* __restrict__ ei, const int* __restrict__ offs, const int* __restrict__ eid,
    const bf16* __restrict__ h2, const float* __restrict__ a_s, const float* __restrict__ a_d,
    const float* __restrict__ bias, float* __restrict__ outp)
{
    const int n = blockIdx.x;
    const int beg = offs[n];
    const int deg = offs[n + 1] - beg;
    const int t = threadIdx.x, lane = t & 63, wave = t >> 6;
    __shared__ float m_sh, den_sh;
    __shared__ float al_sh[64];
    __shared__ int   src_sh[64];
    __shared__ float red[8][32][8];

    if (wave == 0 && deg > 0) {
        const float adn = a_d[n];
        float mx = -INFINITY;
        for (int k = lane; k < deg; k += 64) {
            const int s = ei[N_EDGES + eid[beg + k]];
            float v = a_s[s] + adn;
            v = v > 0.f ? v : NEG_SLOPE * v;
            mx = fmaxf(mx, v);
        }
        #pragma unroll
        for (int o = 32; o > 0; o >>= 1) mx = fmaxf(mx, __shfl_xor(mx, o));
        float sm = 0.f;
        for (int k = lane; k < deg; k += 64) {
            const int s = ei[N_EDGES + eid[beg + k]];
            float v = a_s[s] + adn;
            v = v > 0.f ? v : NEG_SLOPE * v;
            sm += __expf(v - mx);
        }
        #pragma unroll
        for (int o = 32; o > 0; o >>= 1) sm += __shfl_xor(sm, o);
        if (lane == 0) { m_sh = mx; den_sh = sm + 1e-16f; }
    }
    __syncthreads();

    const int g = t >> 5;
    const int l32 = t & 31;
    const int ch = l32 * 8;
    float acc[8] = {0.f, 0.f, 0.f, 0.f, 0.f, 0.f, 0.f, 0.f};

    for (int bs = 0; bs < deg; bs += 64) {
        const int cnt = min(64, deg - bs);
        if (wave == 0 && lane < cnt) {
            const int e = eid[beg + bs + lane];
            const int s = ei[N_EDGES + e];
            src_sh[lane] = s;
            float v = a_s[s] + a_d[n];
            v = v > 0.f ? v : NEG_SLOPE * v;
            al_sh[lane] = __expf(v - m_sh) / den_sh;
        }
        __syncthreads();
        for (int k = 0; k < cnt; k += 8) {
            const int kk = k + g;
            if (kk < cnt) {
                const int s = src_sh[kk];
                const float al = al_sh[kk];
                const uint4 hv = *(const uint4*)(h2 + (size_t)s * OUT_C + ch);
                acc[0] += lo2f(hv.x) * al; acc[1] += hi2f(hv.x) * al;
                acc[2] += lo2f(hv.y) * al; acc[3] += hi2f(hv.y) * al;
                acc[4] += lo2f(hv.z) * al; acc[5] += hi2f(hv.z) * al;
                acc[6] += lo2f(hv.w) * al; acc[7] += hi2f(hv.w) * al;
            }
        }
        __syncthreads();
    }

    #pragma unroll
    for (int j = 0; j < 8; ++j) red[g][l32][j] = acc[j];
    __syncthreads();
    if (g == 0) {
        #pragma unroll
        for (int gg = 1; gg < 8; ++gg)
            #pragma unroll
            for (int j = 0; j < 8; ++j) acc[j] += red[gg][l32][j];
        float4 w0, w1;
        w0.x = acc[0] + bias[ch + 0]; w0.y = acc[1] + bias[ch + 1];
        w0.z = acc[2] + bias[ch + 2]; w0.w = acc[3] + bias[ch + 3];
        w1.x = acc[4] + bias[ch + 4]; w1.y = acc[5] + bias[ch + 5];
        w1.z = acc[6] + bias[ch + 6]; w1.w = acc[7] + bias[ch + 7];
        *(float4*)(outp + (size_t)n * OUT_C + ch)     = w0;
        *(float4*)(outp + (size_t)n * OUT_C + ch + 4) = w1;
    }
}

extern "C" void kernel_launch(void* const* d_in, const int* in_sizes, int n_in,
                              void* d_out, int out_size, void* d_ws, size_t ws_size,
                              hipStream_t stream) {
    (void)in_sizes; (void)n_in; (void)out_size; (void)ws_size;
    const float* x        = (const float*)d_in[0];
    const int*   ei       = (const int*)d_in[1];   // int32 [2,E] (verified round 4)
    const float* W1       = (const float*)d_in[2];
    const float* att_src1 = (const float*)d_in[3];
    const float* att_dst1 = (const float*)d_in[4];
    const float* b1       = (const float*)d_in[5];
    const float* W2       = (const float*)d_in[6];
    const float* att_src2 = (const float*)d_in[7];
    const float* att_dst2 = (const float*)d_in[8];
    const float* b2       = (const float*)d_in[9];
    float* out = (float*)d_out;

    // ---- workspace carve (all 256B-aligned) ----
    char* base = (char*)d_ws;
    size_t woff = 0;
    auto carve = [&](size_t bytes) -> char* {
        char* p = base + woff;
        woff += (bytes + 255) & ~(size_t)255;
        return p;
    };
    bf16* h1   = (bf16*)carve((size_t)N_NODES * H1DIM * 2);   // 20.48 MB
    bf16* a2   = (bf16*)carve((size_t)N_NODES * H1DIM * 2);   // 20.48 MB
    bf16* h2   = (bf16*)carve((size_t)N_NODES * OUT_C * 2);   //  5.12 MB
    bf16* xb   = (bf16*)carve((size_t)N_NODES * IN_C * 2);    // 15.36 MB
    bf16* W1t  = (bf16*)carve((size_t)H1DIM * IN_C * 2);
    bf16* W2t  = (bf16*)carve((size_t)OUT_C * H1DIM * 2);
    // NOTE: as1..degs must stay CONTIGUOUS — prep_kernel zeroes the whole span.
    float* as1 = (float*)carve((size_t)N_NODES * HEADS * 4);  // 160000 B
    float* ad1 = (float*)carve((size_t)N_NODES * HEADS * 4);  // 160000 B
    float* as2 = (float*)carve((size_t)N_NODES * 4);          // 40000 -> 40192 B
    float* ad2 = (float*)carve((size_t)N_NODES * 4);          // 40000 -> 40192 B
    int* degs  = (int*)carve((size_t)4 * N_NODES * 4);        // 160000 B
    int* deg_d = degs;
    int* deg_s = degs + N_NODES;
    int* cur_d = degs + 2 * N_NODES;
    int* cur_s = degs + 3 * N_NODES;
    int* offs_d = (int*)carve((size_t)(N_NODES + 1) * 4);
    int* offs_s = (int*)carve((size_t)(N_NODES + 1) * 4);
    int* eid_d  = (int*)carve((size_t)N_EDGES * 4);
    int* eid_s  = (int*)carve((size_t)N_EDGES * 4);

    // ---- fused prep: cvt + transposes + zero(as1..degs) ----
    prep_kernel<<<CVT_BLOCKS + T1_BLOCKS + T2_BLOCKS + Z_BLOCKS, 256, 0, stream>>>(
        x, xb, W1, W1t, W2, W2t, (int*)as1);

    // ---- CSR build ----
    count_deg<<<(N_EDGES + 255) / 256, 256, 0, stream>>>(ei, deg_d, deg_s);
    scan_fast2<<<2, 1024, 0, stream>>>(deg_d, offs_d, deg_s, offs_s, N_NODES);
    fill_csr<<<(N_EDGES + 255) / 256, 256, 0, stream>>>(ei, offs_d, offs_s, cur_d, cur_s, eid_d, eid_s);

    // ---- layer 1 (128x128 tile: 8 column passes over xb) ----
    gemm_mfma128<<<dim3(H1DIM / 128, (N_NODES + 127) / 128), 256, 0, stream>>>(
        xb, W1t, h1, N_NODES, H1DIM, IN_C);
    att_dots<<<(N_NODES * HEADS + 3) / 4, 256, 0, stream>>>(
        h1, att_src1, att_dst1, as1, ad1, N_NODES * HEADS, HEADS);
    gat_gather1<<<N_NODES, 256, 0, stream>>>(ei, offs_d, eid_d, h1, as1, ad1, b1, a2);

    // ---- layer 2 (128x64 tile keeps >=256 blocks at N=256) ----
    gemm_mfma64<<<dim3(OUT_C / 64, (N_NODES + 127) / 128), 256, 0, stream>>>(
        a2, W2t, h2, N_NODES, OUT_C, H1DIM);
    att_dots<<<(N_NODES + 3) / 4, 256, 0, stream>>>(
        h2, att_src2, att_dst2, as2, ad2, N_NODES, 1);
    gat_gather2<<<N_NODES, 256, 0, stream>>>(ei, offs_s, eid_s, h2, as2, ad2, b2, out);
}